// Round 5
// baseline (16997.600 us; speedup 1.0000x reference)
//
#include <hip/hip_runtime.h>

#define T_TOTAL 8000

typedef unsigned long long ull;

__device__ __forceinline__ float sig_f(float x) { return 1.f / (1.f + __expf(-x)); }
__device__ __forceinline__ float tanh_f(float x) { return 1.f - 2.f / (__expf(2.f * x) + 1.f); }

// ---------------- init: unpack states into epoch-tagged pairs ----------------
// pair: low32 = tag (epoch), high32 = float bits of h. tag e lives in buffer e&1.
// buf0 = (h0, tag 0); buf1 = tag 0 (never matches its first expected tag 1).
__global__ void init_kernel(const float* __restrict__ st, ull* hp, float* cs) {
  int idx = blockIdx.x * blockDim.x + threadIdx.x;
  if (idx < 2048) {  // p*512+u
    unsigned hb = __float_as_uint(st[2 * idx + 0]);
    hp[idx]        = ((ull)hb << 32) | 0ull;
    hp[2048 + idx] = 0ull;               // MUST clear: ws poisoned
    cs[idx] = st[2 * idx + 1];
  }
}

// ---------------- projection: xz[p][t][2048] = x_p @ W_p + b_p ----------------
__global__ __launch_bounds__(256) void proj_kernel(
    const float* __restrict__ in_real, const float* __restrict__ in_imag,
    const float* __restrict__ Wr, const float* __restrict__ br,
    const float* __restrict__ Wi, const float* __restrict__ bi,
    float* __restrict__ xz, int t0, int chunk) {
  const int p = blockIdx.z;
  const float* __restrict__ X = (p < 2) ? in_real : in_imag;
  const float* __restrict__ W = (p & 1) ? Wi : Wr;
  const float* __restrict__ Bv = (p & 1) ? bi : br;
  const int nb = blockIdx.x * 64, mb = blockIdx.y * 64;
  __shared__ float As[16][68];
  __shared__ float Bs[16][68];
  const int tid = threadIdx.x;
  const int tm = tid >> 4, tn = tid & 15;
  const int lam = tid >> 2, lak = (tid & 3) << 2;   // A: row, k-offset
  const int lbk = tid >> 4, lbn = (tid & 15) << 2;  // B: k, col-offset
  float acc[4][4] = {};
  for (int k0 = 0; k0 < 512; k0 += 16) {
    int msafe = mb + lam; if (msafe > chunk - 1) msafe = chunk - 1;
    float4 a4 = *(const float4*)&X[(size_t)(t0 + msafe) * 512 + k0 + lak];
    float4 b4 = *(const float4*)&W[(size_t)(k0 + lbk) * 2048 + nb + lbn];
    __syncthreads();
    As[lak + 0][lam] = a4.x; As[lak + 1][lam] = a4.y;
    As[lak + 2][lam] = a4.z; As[lak + 3][lam] = a4.w;
    *(float4*)&Bs[lbk][lbn] = b4;
    __syncthreads();
#pragma unroll
    for (int k = 0; k < 16; ++k) {
      float4 av = *(const float4*)&As[k][tm << 2];
      float4 bv = *(const float4*)&Bs[k][tn << 2];
      acc[0][0] = fmaf(av.x, bv.x, acc[0][0]); acc[0][1] = fmaf(av.x, bv.y, acc[0][1]);
      acc[0][2] = fmaf(av.x, bv.z, acc[0][2]); acc[0][3] = fmaf(av.x, bv.w, acc[0][3]);
      acc[1][0] = fmaf(av.y, bv.x, acc[1][0]); acc[1][1] = fmaf(av.y, bv.y, acc[1][1]);
      acc[1][2] = fmaf(av.y, bv.z, acc[1][2]); acc[1][3] = fmaf(av.y, bv.w, acc[1][3]);
      acc[2][0] = fmaf(av.z, bv.x, acc[2][0]); acc[2][1] = fmaf(av.z, bv.y, acc[2][1]);
      acc[2][2] = fmaf(av.z, bv.z, acc[2][2]); acc[2][3] = fmaf(av.z, bv.w, acc[2][3]);
      acc[3][0] = fmaf(av.w, bv.x, acc[3][0]); acc[3][1] = fmaf(av.w, bv.y, acc[3][1]);
      acc[3][2] = fmaf(av.w, bv.z, acc[3][2]); acc[3][3] = fmaf(av.w, bv.w, acc[3][3]);
    }
  }
  float4 bias4 = *(const float4*)&Bv[nb + (tn << 2)];
#pragma unroll
  for (int i = 0; i < 4; ++i) {
    int mm = mb + (tm << 2) + i;
    if (mm < chunk) {
      float4 v;
      v.x = acc[i][0] + bias4.x; v.y = acc[i][1] + bias4.y;
      v.z = acc[i][2] + bias4.z; v.w = acc[i][3] + bias4.w;
      *(float4*)&xz[(size_t)(p * chunk + mm) * 2048 + nb + (tn << 2)] = v;
    }
  }
}

// ---------------- persistent recurrent kernel ----------------
// grid = 128 blocks x 256 thr. block: pass p = bx&3, slice g = bx>>2 (16 units).
// wave w owns units U0w..U0w+4 (U0w = g*16+w*4); lane l: unit = l&3, kg = l>>2,
// k-window = kg*32..+32; R slice r[4][32] = 128 regs.
// Step: (a) spin-gather 2 pairs/lane (gather IS the poll, 1KB/wave/retry),
//       (b) stage quarter to padded LDS, lgkm-only barrier,
//       (c) FMA from LDS, butterfly reduce, cell replicated, owners publish one
//       fire-and-forget 8B pair (tag t+1) + ONE PLAIN STORE of hn to the
//       pass-private hseq slab. NO atomics anywhere in the loop: atomicAdd acks
//       (contended cross-XCD RMW lines, ~1us) were being drained by the next
//       spin's vmcnt(0) -> back onto the critical path. hseq stores ack from
//       the local L2, so the spin's vmcnt drain is cheap.
// Complex combination + final states move to combine/final kernels.
__global__ __launch_bounds__(256, 1) void recur_kernel(
    const float* __restrict__ xz, const float* __restrict__ Rr, const float* __restrict__ Ri,
    ull* hp, float* cs, float* __restrict__ hseq, int t0, int chunk) {
  const int tid = threadIdx.x;
  const int w = tid >> 6, l = tid & 63;
  const int un = l & 3, kg = l >> 2;
  const int p = blockIdx.x & 3, g = blockIdx.x >> 2;
  const int U0w = g * 16 + w * 4;
  const float* __restrict__ R = (p & 1) ? Ri : Rr;

  // R slice -> registers (one-time): r[gate][kk], k = kg*32+kk, col = gate*512 + U0w+un
  float r[4][32];
  {
    const float* Rb = R + (size_t)(kg * 32) * 2048 + (U0w + un);
#pragma unroll
    for (int kk = 0; kk < 32; ++kk) {
#pragma unroll
      for (int gg = 0; gg < 4; ++gg) r[gg][kk] = Rb[(size_t)kk * 2048 + gg * 512];
    }
  }

  // padded LDS h-stage: h[k] at row k>>5, col k&31, stride 36 (2-way bank max)
  __shared__ float hsh[2][16 * 36];
  const int wrow = w * 4 + (l >> 4);          // staging: k = w*128 + 2l
  const int wcol = (2 * l) & 31;
  float c_old = cs[p * 512 + U0w + un];       // replicated across the 16 lanes of a unit

  for (int tl = 0; tl < chunk; ++tl) {
    const int t = t0 + tl;
    // xz prefetch (cached loads; latency hides under the spin)
    float xzv[4];
    {
      const float* xr = xz + ((size_t)p * chunk + tl) * 2048 + (U0w + un);
#pragma unroll
      for (int gg = 0; gg < 4; ++gg) xzv[gg] = xr[gg * 512];
    }

    // (a) spin-gather own 2 pairs of this wave's k-quarter
    const ull* gp = hp + (t & 1) * 2048 + p * 512 + w * 128 + 2 * l;
    const unsigned tgt = (unsigned)t;
    ull q0, q1;
    for (;;) {
      q0 = __hip_atomic_load(gp + 0, __ATOMIC_RELAXED, __HIP_MEMORY_SCOPE_AGENT);
      q1 = __hip_atomic_load(gp + 1, __ATOMIC_RELAXED, __HIP_MEMORY_SCOPE_AGENT);
      if (__all(((unsigned)q0 == tgt) & ((unsigned)q1 == tgt))) break;
    }

    // (b) stage to LDS, lgkm-only barrier (NOT __syncthreads: no vmcnt drain)
    {
      float2 hv2 = make_float2(__uint_as_float((unsigned)(q0 >> 32)),
                               __uint_as_float((unsigned)(q1 >> 32)));
      *(float2*)&hsh[t & 1][wrow * 36 + wcol] = hv2;
    }
    asm volatile("s_waitcnt lgkmcnt(0)" ::: "memory");
    __builtin_amdgcn_s_barrier();
    asm volatile("" ::: "memory");

    // (c) GEMV from LDS broadcast reads: 8 x float4 of own k-window
    const float* rp = &hsh[t & 1][kg * 36];
    float a[4] = {0.f, 0.f, 0.f, 0.f};
#pragma unroll
    for (int q = 0; q < 8; ++q) {
      float4 h4 = *(const float4*)(rp + 4 * q);
#pragma unroll
      for (int gg = 0; gg < 4; ++gg) {
        a[gg] = fmaf(r[gg][4 * q + 0], h4.x, a[gg]);
        a[gg] = fmaf(r[gg][4 * q + 1], h4.y, a[gg]);
        a[gg] = fmaf(r[gg][4 * q + 2], h4.z, a[gg]);
        a[gg] = fmaf(r[gg][4 * q + 3], h4.w, a[gg]);
      }
    }
    // butterfly over the 16 lanes of this unit (lane bits 2..5)
#pragma unroll
    for (int gg = 0; gg < 4; ++gg) {
      a[gg] += __shfl_xor(a[gg], 4);
      a[gg] += __shfl_xor(a[gg], 8);
      a[gg] += __shfl_xor(a[gg], 16);
      a[gg] += __shfl_xor(a[gg], 32);
    }
    const float zi = a[0] + xzv[0], zf = a[1] + xzv[1];
    const float zg = a[2] + xzv[2], zo = a[3] + xzv[3];
    const float cn = sig_f(zf) * c_old + sig_f(zi) * tanh_f(zg);
    const float hn = sig_f(zo) * tanh_f(cn);
    c_old = cn;  // identical across the unit's 16 lanes

    // publish pair (fire-and-forget) + plain hseq store (uncontended, local-L2 ack)
    if (l < 4) {
      ull pv = ((ull)__float_as_uint(hn) << 32) | (ull)(unsigned)(t + 1);
      __hip_atomic_store(&hp[((t + 1) & 1) * 2048 + p * 512 + U0w + l], pv,
                         __ATOMIC_RELAXED, __HIP_MEMORY_SCOPE_AGENT);
      hseq[((size_t)p * chunk + tl) * 512 + U0w + l] = hn;
    }
  }
  if (l < 4) cs[p * 512 + U0w + l] = c_old;
}

// ---------------- combine: real = r2r - i2i, imag = r2i + i2r ----------------
// hseq[p][tl][u] (f32), chunk*512 elems per pass. float4-vectorized, mem-bound.
__global__ __launch_bounds__(256) void combine_kernel(
    const float* __restrict__ hseq, float* __restrict__ out, int t0, int chunk) {
  const size_t n4 = (size_t)chunk * 512 / 4;
  const size_t idx = (size_t)blockIdx.x * 256 + threadIdx.x;
  if (idx >= n4) return;
  const size_t pstride = (size_t)chunk * 512;
  float4 h0 = *(const float4*)&hseq[0 * pstride + 4 * idx];  // r2r
  float4 h1 = *(const float4*)&hseq[1 * pstride + 4 * idx];  // r2i
  float4 h2 = *(const float4*)&hseq[2 * pstride + 4 * idx];  // i2r
  float4 h3 = *(const float4*)&hseq[3 * pstride + 4 * idx];  // i2i
  float4 re, im;
  re.x = h0.x - h3.x; re.y = h0.y - h3.y; re.z = h0.z - h3.z; re.w = h0.w - h3.w;
  im.x = h1.x + h2.x; im.y = h1.y + h2.y; im.z = h1.z + h2.z; im.w = h1.w + h2.w;
  *(float4*)&out[(size_t)t0 * 512 + 4 * idx] = re;
  *(float4*)&out[(size_t)4096000 + (size_t)t0 * 512 + 4 * idx] = im;
}

// ---------------- final states: h from last hseq step, c from cs ----------------
__global__ void final_kernel(const float* __restrict__ hseq, const float* __restrict__ cs,
                             float* __restrict__ out, int chunk) {
  int idx = blockIdx.x * blockDim.x + threadIdx.x;
  if (idx < 2048) {  // p*512+u
    const int p = idx >> 9, u = idx & 511;
    out[8192000 + 2 * (size_t)idx + 0] = hseq[((size_t)p * chunk + (chunk - 1)) * 512 + u];
    out[8192000 + 2 * (size_t)idx + 1] = cs[idx];
  }
}

extern "C" void kernel_launch(void* const* d_in, const int* in_sizes, int n_in,
                              void* d_out, int out_size, void* d_ws, size_t ws_size,
                              hipStream_t stream) {
  (void)in_sizes; (void)n_in;
  const float* in_real   = (const float*)d_in[0];
  const float* in_imag   = (const float*)d_in[1];
  const float* in_states = (const float*)d_in[2];
  const float* Wr = (const float*)d_in[3];
  const float* Rr = (const float*)d_in[4];
  const float* br = (const float*)d_in[5];
  const float* Wi = (const float*)d_in[6];
  const float* Ri = (const float*)d_in[7];
  const float* bi = (const float*)d_in[8];
  float* out = (float*)d_out;

  // ws layout: h pair double-buffer [2][4][512] x 8B (32KB) | c [4][512] (8KB)
  //            | pad to 64KB | xz chunk [4][chunk][2048] | hseq [4][chunk][512]
  ull* hp = (ull*)d_ws;
  float* cs = (float*)((char*)d_ws + 32768);
  float* xz = (float*)((char*)d_ws + 65536);

  int chunk = 2000;  // halvings all divide 8000
  // per-chunk bytes: xz 4*2048*4*chunk + hseq 4*512*4*chunk = 40960*chunk
  while (chunk > 125 && (size_t)chunk * 40960 + 65536 > ws_size) chunk >>= 1;
  float* hseq = xz + (size_t)4 * chunk * 2048;

  hipMemsetAsync(d_out, 0, (size_t)out_size * sizeof(float), stream);
  init_kernel<<<2, 1024, 0, stream>>>(in_states, hp, cs);
  for (int t0 = 0; t0 < T_TOTAL; t0 += chunk) {
    dim3 pgrid(2048 / 64, (chunk + 63) / 64, 4);
    proj_kernel<<<pgrid, 256, 0, stream>>>(in_real, in_imag, Wr, br, Wi, bi, xz, t0, chunk);
    recur_kernel<<<128, 256, 0, stream>>>(xz, Rr, Ri, hp, cs, hseq, t0, chunk);
    combine_kernel<<<(chunk * 512 / 4 + 255) / 256, 256, 0, stream>>>(hseq, out, t0, chunk);
  }
  final_kernel<<<2, 1024, 0, stream>>>(hseq, cs, out, chunk);
}

// Round 7
// 16665.495 us; speedup vs baseline: 1.0199x; 1.0199x over previous
//
#include <hip/hip_runtime.h>

#define T_TOTAL 8000

typedef unsigned long long ull;

__device__ __forceinline__ float sig_f(float x) { return 1.f / (1.f + __expf(-x)); }
__device__ __forceinline__ float tanh_f(float x) { return 1.f - 2.f / (__expf(2.f * x) + 1.f); }

// ---------------- init: unpack states into epoch-tagged pairs ----------------
// pair: low32 = tag (epoch), high32 = float bits of h. tag e lives in buffer e&1.
// Both slabs (fast: XCD-L2 path, slow: LLC path) get identical init.
__global__ void init_kernel(const float* __restrict__ st, ull* hpF, ull* hpS, float* cs) {
  int idx = blockIdx.x * blockDim.x + threadIdx.x;
  if (idx < 2048) {  // p*512+u
    unsigned hb = __float_as_uint(st[2 * idx + 0]);
    ull p0 = ((ull)hb << 32) | 0ull;
    hpF[idx] = p0;        hpS[idx] = p0;
    hpF[2048 + idx] = 0;  hpS[2048 + idx] = 0;   // MUST clear: ws poisoned
    cs[idx] = st[2 * idx + 1];
  }
}

// ---------------- projection: xz[p][t][2048] = x_p @ W_p + b_p ----------------
__global__ __launch_bounds__(256) void proj_kernel(
    const float* __restrict__ in_real, const float* __restrict__ in_imag,
    const float* __restrict__ Wr, const float* __restrict__ br,
    const float* __restrict__ Wi, const float* __restrict__ bi,
    float* __restrict__ xz, int t0, int chunk) {
  const int p = blockIdx.z;
  const float* __restrict__ X = (p < 2) ? in_real : in_imag;
  const float* __restrict__ W = (p & 1) ? Wi : Wr;
  const float* __restrict__ Bv = (p & 1) ? bi : br;
  const int nb = blockIdx.x * 64, mb = blockIdx.y * 64;
  __shared__ float As[16][68];
  __shared__ float Bs[16][68];
  const int tid = threadIdx.x;
  const int tm = tid >> 4, tn = tid & 15;
  const int lam = tid >> 2, lak = (tid & 3) << 2;   // A: row, k-offset
  const int lbk = tid >> 4, lbn = (tid & 15) << 2;  // B: k, col-offset
  float acc[4][4] = {};
  for (int k0 = 0; k0 < 512; k0 += 16) {
    int msafe = mb + lam; if (msafe > chunk - 1) msafe = chunk - 1;
    float4 a4 = *(const float4*)&X[(size_t)(t0 + msafe) * 512 + k0 + lak];
    float4 b4 = *(const float4*)&W[(size_t)(k0 + lbk) * 2048 + nb + lbn];
    __syncthreads();
    As[lak + 0][lam] = a4.x; As[lak + 1][lam] = a4.y;
    As[lak + 2][lam] = a4.z; As[lak + 3][lam] = a4.w;
    *(float4*)&Bs[lbk][lbn] = b4;
    __syncthreads();
#pragma unroll
    for (int k = 0; k < 16; ++k) {
      float4 av = *(const float4*)&As[k][tm << 2];
      float4 bv = *(const float4*)&Bs[k][tn << 2];
      acc[0][0] = fmaf(av.x, bv.x, acc[0][0]); acc[0][1] = fmaf(av.x, bv.y, acc[0][1]);
      acc[0][2] = fmaf(av.x, bv.z, acc[0][2]); acc[0][3] = fmaf(av.x, bv.w, acc[0][3]);
      acc[1][0] = fmaf(av.y, bv.x, acc[1][0]); acc[1][1] = fmaf(av.y, bv.y, acc[1][1]);
      acc[1][2] = fmaf(av.y, bv.z, acc[1][2]); acc[1][3] = fmaf(av.y, bv.w, acc[1][3]);
      acc[2][0] = fmaf(av.z, bv.x, acc[2][0]); acc[2][1] = fmaf(av.z, bv.y, acc[2][1]);
      acc[2][2] = fmaf(av.z, bv.z, acc[2][2]); acc[2][3] = fmaf(av.z, bv.w, acc[2][3]);
      acc[3][0] = fmaf(av.w, bv.x, acc[3][0]); acc[3][1] = fmaf(av.w, bv.y, acc[3][1]);
      acc[3][2] = fmaf(av.w, bv.z, acc[3][2]); acc[3][3] = fmaf(av.w, bv.w, acc[3][3]);
    }
  }
  float4 bias4 = *(const float4*)&Bv[nb + (tn << 2)];
#pragma unroll
  for (int i = 0; i < 4; ++i) {
    int mm = mb + (tm << 2) + i;
    if (mm < chunk) {
      float4 v;
      v.x = acc[i][0] + bias4.x; v.y = acc[i][1] + bias4.y;
      v.z = acc[i][2] + bias4.z; v.w = acc[i][3] + bias4.w;
      *(float4*)&xz[(size_t)(p * chunk + mm) * 2048 + nb + (tn << 2)] = v;
    }
  }
}

// ---------------- persistent recurrent kernel ----------------
// grid = 256 blocks x 256 thr (1/CU). Active iff bx%8 < 4: pass p = bx&7,
// slice g = bx>>3 in [0,32). Under round-robin bx%8->XCD, a pass's 32 WGs
// land on ONE XCD, so its h exchange can resolve in that XCD's shared L2.
// Exchange is DUAL-PUBLISHED so no placement assumption affects correctness:
//   fast slab: plain 8B store (dirty in producer's L2; same-XCD sc0 loads see
//              it at ~200cy RT). Cross-XCD consumers just see stale tags.
//   slow slab: agent-scope atomic store (LLC-visible to all, r5 semantics).
// Consumer spin alternates 3 fast sc0 rounds : 1 slow agent round, sticky
// per-pair accept on tag==t. Slow rounds guarantee progress -> CANNOT hang;
// tags reject stale data; aligned 8B single-instr ops cannot tear.
// Step structure unchanged from r5 (LDS stage, butterfly, hseq, no atomics).
__global__ __launch_bounds__(256, 1) void recur_kernel(
    const float* __restrict__ xz, const float* __restrict__ Rr, const float* __restrict__ Ri,
    ull* hpF, ull* hpS, float* cs, float* __restrict__ hseq, int t0, int chunk) {
  const int bx = blockIdx.x;
  if ((bx & 7) >= 4) return;              // filler block (XCD alignment only)
  const int p = bx & 7, g = bx >> 3;
  const int tid = threadIdx.x;
  const int w = tid >> 6, l = tid & 63;
  const int un = l & 3, kg = l >> 2;
  const int U0w = g * 16 + w * 4;
  const float* __restrict__ R = (p & 1) ? Ri : Rr;

  // R slice -> registers (one-time): r[gate][kk], k = kg*32+kk, col = gate*512 + U0w+un
  float r[4][32];
  {
    const float* Rb = R + (size_t)(kg * 32) * 2048 + (U0w + un);
#pragma unroll
    for (int kk = 0; kk < 32; ++kk) {
#pragma unroll
      for (int gg = 0; gg < 4; ++gg) r[gg][kk] = Rb[(size_t)kk * 2048 + gg * 512];
    }
  }

  // padded LDS h-stage: h[k] at row k>>5, col k&31, stride 36 (2-way bank max)
  __shared__ float hsh[2][16 * 36];
  const int wrow = w * 4 + (l >> 4);          // staging: k = w*128 + 2l
  const int wcol = (2 * l) & 31;
  float c_old = cs[p * 512 + U0w + un];       // replicated across the 16 lanes of a unit

  for (int tl = 0; tl < chunk; ++tl) {
    const int t = t0 + tl;
    // xz prefetch (cached loads; latency hides under the spin)
    float xzv[4];
    {
      const float* xr = xz + ((size_t)p * chunk + tl) * 2048 + (U0w + un);
#pragma unroll
      for (int gg = 0; gg < 4; ++gg) xzv[gg] = xr[gg * 512];
    }

    // (a) spin-gather own 2 pairs: fast (XCD-L2, sc0) with periodic slow
    //     (LLC, agent) fallback rounds; sticky accept per pair on tag==t.
    const size_t poff = (size_t)(t & 1) * 2048 + p * 512 + w * 128 + 2 * l;
    const ull* gpF = hpF + poff;
    const ull* gpS = hpS + poff;
    const unsigned tgt = (unsigned)t;
    ull q0 = 0, q1 = 0;
    unsigned v0 = 0, v1 = 0;
    for (int it = 0;; ++it) {
      ull a0, a1;
      if ((it & 3) == 3) {  // slow round: always-correct LLC path
        a0 = __hip_atomic_load(gpS + 0, __ATOMIC_RELAXED, __HIP_MEMORY_SCOPE_AGENT);
        a1 = __hip_atomic_load(gpS + 1, __ATOMIC_RELAXED, __HIP_MEMORY_SCOPE_AGENT);
      } else {              // fast round: bypass L1, read this XCD's L2
        asm volatile("global_load_dwordx2 %0, %2, off sc0\n\t"
                     "global_load_dwordx2 %1, %2, off offset:8 sc0\n\t"
                     "s_waitcnt vmcnt(0)"
                     : "=&v"(a0), "=&v"(a1) : "v"(gpF) : "memory");
      }
      if (!v0 && (unsigned)a0 == tgt) { q0 = a0; v0 = 1; }
      if (!v1 && (unsigned)a1 == tgt) { q1 = a1; v1 = 1; }
      if (__all(v0 & v1)) break;
    }

    // (b) stage to LDS, lgkm-only barrier (NOT __syncthreads: no vmcnt drain)
    {
      float2 hv2 = make_float2(__uint_as_float((unsigned)(q0 >> 32)),
                               __uint_as_float((unsigned)(q1 >> 32)));
      *(float2*)&hsh[t & 1][wrow * 36 + wcol] = hv2;
    }
    asm volatile("s_waitcnt lgkmcnt(0)" ::: "memory");
    __builtin_amdgcn_s_barrier();
    asm volatile("" ::: "memory");

    // (c) GEMV from LDS broadcast reads: 8 x float4 of own k-window
    const float* rp = &hsh[t & 1][kg * 36];
    float a[4] = {0.f, 0.f, 0.f, 0.f};
#pragma unroll
    for (int q = 0; q < 8; ++q) {
      float4 h4 = *(const float4*)(rp + 4 * q);
#pragma unroll
      for (int gg = 0; gg < 4; ++gg) {
        a[gg] = fmaf(r[gg][4 * q + 0], h4.x, a[gg]);
        a[gg] = fmaf(r[gg][4 * q + 1], h4.y, a[gg]);
        a[gg] = fmaf(r[gg][4 * q + 2], h4.z, a[gg]);
        a[gg] = fmaf(r[gg][4 * q + 3], h4.w, a[gg]);
      }
    }
    // butterfly over the 16 lanes of this unit (lane bits 2..5)
#pragma unroll
    for (int gg = 0; gg < 4; ++gg) {
      a[gg] += __shfl_xor(a[gg], 4);
      a[gg] += __shfl_xor(a[gg], 8);
      a[gg] += __shfl_xor(a[gg], 16);
      a[gg] += __shfl_xor(a[gg], 32);
    }
    const float zi = a[0] + xzv[0], zf = a[1] + xzv[1];
    const float zg = a[2] + xzv[2], zo = a[3] + xzv[3];
    const float cn = sig_f(zf) * c_old + sig_f(zi) * tanh_f(zg);
    const float hn = sig_f(zo) * tanh_f(cn);
    c_old = cn;  // identical across the unit's 16 lanes

    // dual-publish (both fire-and-forget) + plain hseq store
    if (l < 4) {
      ull pv = ((ull)__float_as_uint(hn) << 32) | (ull)(unsigned)(t + 1);
      const size_t doff = (size_t)((t + 1) & 1) * 2048 + p * 512 + U0w + l;
      ull* dF = hpF + doff;
      asm volatile("global_store_dwordx2 %0, %1, off" :: "v"(dF), "v"(pv) : "memory");
      __hip_atomic_store(hpS + doff, pv, __ATOMIC_RELAXED, __HIP_MEMORY_SCOPE_AGENT);
      hseq[((size_t)p * chunk + tl) * 512 + U0w + l] = hn;
    }
  }
  if (l < 4) cs[p * 512 + U0w + l] = c_old;
}

// ---------------- combine: real = r2r - i2i, imag = r2i + i2r ----------------
__global__ __launch_bounds__(256) void combine_kernel(
    const float* __restrict__ hseq, float* __restrict__ out, int t0, int chunk) {
  const size_t n4 = (size_t)chunk * 512 / 4;
  const size_t idx = (size_t)blockIdx.x * 256 + threadIdx.x;
  if (idx >= n4) return;
  const size_t pstride = (size_t)chunk * 512;
  float4 h0 = *(const float4*)&hseq[0 * pstride + 4 * idx];  // r2r
  float4 h1 = *(const float4*)&hseq[1 * pstride + 4 * idx];  // r2i
  float4 h2 = *(const float4*)&hseq[2 * pstride + 4 * idx];  // i2r
  float4 h3 = *(const float4*)&hseq[3 * pstride + 4 * idx];  // i2i
  float4 re, im;
  re.x = h0.x - h3.x; re.y = h0.y - h3.y; re.z = h0.z - h3.z; re.w = h0.w - h3.w;
  im.x = h1.x + h2.x; im.y = h1.y + h2.y; im.z = h1.z + h2.z; im.w = h1.w + h2.w;
  *(float4*)&out[(size_t)t0 * 512 + 4 * idx] = re;
  *(float4*)&out[(size_t)4096000 + (size_t)t0 * 512 + 4 * idx] = im;
}

// ---------------- final states: h from last hseq step, c from cs ----------------
__global__ void final_kernel(const float* __restrict__ hseq, const float* __restrict__ cs,
                             float* __restrict__ out, int chunk) {
  int idx = blockIdx.x * blockDim.x + threadIdx.x;
  if (idx < 2048) {  // p*512+u
    const int p = idx >> 9, u = idx & 511;
    out[8192000 + 2 * (size_t)idx + 0] = hseq[((size_t)p * chunk + (chunk - 1)) * 512 + u];
    out[8192000 + 2 * (size_t)idx + 1] = cs[idx];
  }
}

extern "C" void kernel_launch(void* const* d_in, const int* in_sizes, int n_in,
                              void* d_out, int out_size, void* d_ws, size_t ws_size,
                              hipStream_t stream) {
  (void)in_sizes; (void)n_in;
  const float* in_real   = (const float*)d_in[0];
  const float* in_imag   = (const float*)d_in[1];
  const float* in_states = (const float*)d_in[2];
  const float* Wr = (const float*)d_in[3];
  const float* Rr = (const float*)d_in[4];
  const float* br = (const float*)d_in[5];
  const float* Wi = (const float*)d_in[6];
  const float* Ri = (const float*)d_in[7];
  const float* bi = (const float*)d_in[8];
  float* out = (float*)d_out;

  // ws layout: fast slab [2][2048]x8B (32KB) | slow slab (32KB) | c (8KB)
  //            | pad to 128KB | xz [4][chunk][2048] | hseq [4][chunk][512]
  ull* hpF = (ull*)d_ws;
  ull* hpS = (ull*)((char*)d_ws + 32768);
  float* cs = (float*)((char*)d_ws + 65536);
  float* xz = (float*)((char*)d_ws + 131072);

  int chunk = 2000;  // halvings all divide 8000
  // per-chunk bytes: xz 4*2048*4*chunk + hseq 4*512*4*chunk = 40960*chunk
  while (chunk > 125 && (size_t)chunk * 40960 + 131072 > ws_size) chunk >>= 1;
  float* hseq = xz + (size_t)4 * chunk * 2048;

  hipMemsetAsync(d_out, 0, (size_t)out_size * sizeof(float), stream);
  init_kernel<<<2, 1024, 0, stream>>>(in_states, hpF, hpS, cs);
  for (int t0 = 0; t0 < T_TOTAL; t0 += chunk) {
    dim3 pgrid(2048 / 64, (chunk + 63) / 64, 4);
    proj_kernel<<<pgrid, 256, 0, stream>>>(in_real, in_imag, Wr, br, Wi, bi, xz, t0, chunk);
    recur_kernel<<<256, 256, 0, stream>>>(xz, Rr, Ri, hpF, hpS, cs, hseq, t0, chunk);
    combine_kernel<<<(chunk * 512 / 4 + 255) / 256, 256, 0, stream>>>(hseq, out, t0, chunk);
  }
  final_kernel<<<2, 1024, 0, stream>>>(hseq, cs, out, chunk);
}

// Round 8
// 12932.349 us; speedup vs baseline: 1.3143x; 1.2887x over previous
//
#include <hip/hip_runtime.h>

#define T_TOTAL 8000

typedef unsigned long long ull;

__device__ __forceinline__ float sig_f(float x) { return 1.f / (1.f + __expf(-x)); }
__device__ __forceinline__ float tanh_f(float x) { return 1.f - 2.f / (__expf(2.f * x) + 1.f); }

// ---------------- init: unpack states into epoch-tagged pairs ----------------
// pair: low32 = tag (epoch), high32 = float bits of h. tag e lives in buffer e&1.
// buf0 = (h0, tag 0); buf1 = tag 0 (never matches its first expected tag 1).
__global__ void init_kernel(const float* __restrict__ st, ull* hp, float* cs) {
  int idx = blockIdx.x * blockDim.x + threadIdx.x;
  if (idx < 2048) {  // p*512+u
    unsigned hb = __float_as_uint(st[2 * idx + 0]);
    hp[idx]        = ((ull)hb << 32) | 0ull;
    hp[2048 + idx] = 0ull;               // MUST clear: ws poisoned
    cs[idx] = st[2 * idx + 1];
  }
}

// ---------------- projection: xz[p][t][2048] = x_p @ W_p + b_p ----------------
__global__ __launch_bounds__(256) void proj_kernel(
    const float* __restrict__ in_real, const float* __restrict__ in_imag,
    const float* __restrict__ Wr, const float* __restrict__ br,
    const float* __restrict__ Wi, const float* __restrict__ bi,
    float* __restrict__ xz, int t0, int chunk) {
  const int p = blockIdx.z;
  const float* __restrict__ X = (p < 2) ? in_real : in_imag;
  const float* __restrict__ W = (p & 1) ? Wi : Wr;
  const float* __restrict__ Bv = (p & 1) ? bi : br;
  const int nb = blockIdx.x * 64, mb = blockIdx.y * 64;
  __shared__ float As[16][68];
  __shared__ float Bs[16][68];
  const int tid = threadIdx.x;
  const int tm = tid >> 4, tn = tid & 15;
  const int lam = tid >> 2, lak = (tid & 3) << 2;   // A: row, k-offset
  const int lbk = tid >> 4, lbn = (tid & 15) << 2;  // B: k, col-offset
  float acc[4][4] = {};
  for (int k0 = 0; k0 < 512; k0 += 16) {
    int msafe = mb + lam; if (msafe > chunk - 1) msafe = chunk - 1;
    float4 a4 = *(const float4*)&X[(size_t)(t0 + msafe) * 512 + k0 + lak];
    float4 b4 = *(const float4*)&W[(size_t)(k0 + lbk) * 2048 + nb + lbn];
    __syncthreads();
    As[lak + 0][lam] = a4.x; As[lak + 1][lam] = a4.y;
    As[lak + 2][lam] = a4.z; As[lak + 3][lam] = a4.w;
    *(float4*)&Bs[lbk][lbn] = b4;
    __syncthreads();
#pragma unroll
    for (int k = 0; k < 16; ++k) {
      float4 av = *(const float4*)&As[k][tm << 2];
      float4 bv = *(const float4*)&Bs[k][tn << 2];
      acc[0][0] = fmaf(av.x, bv.x, acc[0][0]); acc[0][1] = fmaf(av.x, bv.y, acc[0][1]);
      acc[0][2] = fmaf(av.x, bv.z, acc[0][2]); acc[0][3] = fmaf(av.x, bv.w, acc[0][3]);
      acc[1][0] = fmaf(av.y, bv.x, acc[1][0]); acc[1][1] = fmaf(av.y, bv.y, acc[1][1]);
      acc[1][2] = fmaf(av.y, bv.z, acc[1][2]); acc[1][3] = fmaf(av.y, bv.w, acc[1][3]);
      acc[2][0] = fmaf(av.z, bv.x, acc[2][0]); acc[2][1] = fmaf(av.z, bv.y, acc[2][1]);
      acc[2][2] = fmaf(av.z, bv.z, acc[2][2]); acc[2][3] = fmaf(av.z, bv.w, acc[2][3]);
      acc[3][0] = fmaf(av.w, bv.x, acc[3][0]); acc[3][1] = fmaf(av.w, bv.y, acc[3][1]);
      acc[3][2] = fmaf(av.w, bv.z, acc[3][2]); acc[3][3] = fmaf(av.w, bv.w, acc[3][3]);
    }
  }
  float4 bias4 = *(const float4*)&Bv[nb + (tn << 2)];
#pragma unroll
  for (int i = 0; i < 4; ++i) {
    int mm = mb + (tm << 2) + i;
    if (mm < chunk) {
      float4 v;
      v.x = acc[i][0] + bias4.x; v.y = acc[i][1] + bias4.y;
      v.z = acc[i][2] + bias4.z; v.w = acc[i][3] + bias4.w;
      *(float4*)&xz[(size_t)(p * chunk + mm) * 2048 + nb + (tn << 2)] = v;
    }
  }
}

// ---------------- persistent recurrent kernel ----------------
// grid = 128 blocks x 256 thr. block: pass p = bx&3, slice g = bx>>2 (16 units).
// wave w owns units U0w..U0w+4 (U0w = g*16+w*4); lane l: unit = l&3, kg = l>>2,
// k-window = kg*32..+32; R slice r[4][32] = 128 regs.
// Exchange = r5 protocol (epoch pairs, agent-scope relaxed atomics, tiny spin).
// NEW vs r5: xz loads are software-pipelined ONE STEP AHEAD. xz is a 64MB
// streamed slab -> every read is an HBM miss (~900cy). r5 issued them ~10
// instrs before the spin, whose first s_waitcnt vmcnt(0) DRAINED them --
// putting the HBM fetch on the critical path every step (r5/r7 neutrality of
// sync-path fixes pointed here). Now step t+1's loads issue right after step
// t's stage-barrier and complete under GEMV+cell+publish+inter-WG wait; the
// next spin waits on h-probes only.
__global__ __launch_bounds__(256, 1) void recur_kernel(
    const float* __restrict__ xz, const float* __restrict__ Rr, const float* __restrict__ Ri,
    ull* hp, float* cs, float* __restrict__ hseq, int t0, int chunk) {
  const int tid = threadIdx.x;
  const int w = tid >> 6, l = tid & 63;
  const int un = l & 3, kg = l >> 2;
  const int p = blockIdx.x & 3, g = blockIdx.x >> 2;
  const int U0w = g * 16 + w * 4;
  const float* __restrict__ R = (p & 1) ? Ri : Rr;

  // R slice -> registers (one-time): r[gate][kk], k = kg*32+kk, col = gate*512 + U0w+un
  float r[4][32];
  {
    const float* Rb = R + (size_t)(kg * 32) * 2048 + (U0w + un);
#pragma unroll
    for (int kk = 0; kk < 32; ++kk) {
#pragma unroll
      for (int gg = 0; gg < 4; ++gg) r[gg][kk] = Rb[(size_t)kk * 2048 + gg * 512];
    }
  }

  // padded LDS h-stage: h[k] at row k>>5, col k&31, stride 36 (2-way bank max)
  __shared__ float hsh[2][16 * 36];
  const int wrow = w * 4 + (l >> 4);          // staging: k = w*128 + 2l
  const int wcol = (2 * l) & 31;
  float c_old = cs[p * 512 + U0w + un];       // replicated across the 16 lanes of a unit

  // prefetch xz for step 0 (completes under the first spin)
  float xzn[4];
  {
    const float* xr = xz + (size_t)p * chunk * 2048 + (U0w + un);
#pragma unroll
    for (int gg = 0; gg < 4; ++gg) xzn[gg] = xr[gg * 512];
  }

  for (int tl = 0; tl < chunk; ++tl) {
    const int t = t0 + tl;
    // consume the prefetched xz (loads issued last iteration; the spin's
    // vmcnt(0) below guarantees completion before the cell reads them)
    float xzv[4];
#pragma unroll
    for (int gg = 0; gg < 4; ++gg) xzv[gg] = xzn[gg];

    // (a) spin-gather own 2 pairs of this wave's k-quarter
    const ull* gp = hp + (t & 1) * 2048 + p * 512 + w * 128 + 2 * l;
    const unsigned tgt = (unsigned)t;
    ull q0, q1;
    for (;;) {
      q0 = __hip_atomic_load(gp + 0, __ATOMIC_RELAXED, __HIP_MEMORY_SCOPE_AGENT);
      q1 = __hip_atomic_load(gp + 1, __ATOMIC_RELAXED, __HIP_MEMORY_SCOPE_AGENT);
      if (__all(((unsigned)q0 == tgt) & ((unsigned)q1 == tgt))) break;
    }

    // (b) stage to LDS, lgkm-only barrier (NOT __syncthreads: no vmcnt drain)
    {
      float2 hv2 = make_float2(__uint_as_float((unsigned)(q0 >> 32)),
                               __uint_as_float((unsigned)(q1 >> 32)));
      *(float2*)&hsh[t & 1][wrow * 36 + wcol] = hv2;
    }
    asm volatile("s_waitcnt lgkmcnt(0)" ::: "memory");
    __builtin_amdgcn_s_barrier();
    asm volatile("" ::: "memory");

    // issue NEXT step's xz loads now: they hide under GEMV+cell+publish+wait
    if (tl + 1 < chunk) {
      const float* xr = xz + ((size_t)p * chunk + tl + 1) * 2048 + (U0w + un);
#pragma unroll
      for (int gg = 0; gg < 4; ++gg) xzn[gg] = xr[gg * 512];
    }

    // (c) GEMV from LDS broadcast reads: 8 x float4 of own k-window
    const float* rp = &hsh[t & 1][kg * 36];
    float a[4] = {0.f, 0.f, 0.f, 0.f};
#pragma unroll
    for (int q = 0; q < 8; ++q) {
      float4 h4 = *(const float4*)(rp + 4 * q);
#pragma unroll
      for (int gg = 0; gg < 4; ++gg) {
        a[gg] = fmaf(r[gg][4 * q + 0], h4.x, a[gg]);
        a[gg] = fmaf(r[gg][4 * q + 1], h4.y, a[gg]);
        a[gg] = fmaf(r[gg][4 * q + 2], h4.z, a[gg]);
        a[gg] = fmaf(r[gg][4 * q + 3], h4.w, a[gg]);
      }
    }
    // butterfly over the 16 lanes of this unit (lane bits 2..5)
#pragma unroll
    for (int gg = 0; gg < 4; ++gg) {
      a[gg] += __shfl_xor(a[gg], 4);
      a[gg] += __shfl_xor(a[gg], 8);
      a[gg] += __shfl_xor(a[gg], 16);
      a[gg] += __shfl_xor(a[gg], 32);
    }
    const float zi = a[0] + xzv[0], zf = a[1] + xzv[1];
    const float zg = a[2] + xzv[2], zo = a[3] + xzv[3];
    const float cn = sig_f(zf) * c_old + sig_f(zi) * tanh_f(zg);
    const float hn = sig_f(zo) * tanh_f(cn);
    c_old = cn;  // identical across the unit's 16 lanes

    // publish pair (fire-and-forget) + plain hseq store (uncontended)
    if (l < 4) {
      ull pv = ((ull)__float_as_uint(hn) << 32) | (ull)(unsigned)(t + 1);
      __hip_atomic_store(&hp[((t + 1) & 1) * 2048 + p * 512 + U0w + l], pv,
                         __ATOMIC_RELAXED, __HIP_MEMORY_SCOPE_AGENT);
      hseq[((size_t)p * chunk + tl) * 512 + U0w + l] = hn;
    }
  }
  if (l < 4) cs[p * 512 + U0w + l] = c_old;
}

// ---------------- combine: real = r2r - i2i, imag = r2i + i2r ----------------
__global__ __launch_bounds__(256) void combine_kernel(
    const float* __restrict__ hseq, float* __restrict__ out, int t0, int chunk) {
  const size_t n4 = (size_t)chunk * 512 / 4;
  const size_t idx = (size_t)blockIdx.x * 256 + threadIdx.x;
  if (idx >= n4) return;
  const size_t pstride = (size_t)chunk * 512;
  float4 h0 = *(const float4*)&hseq[0 * pstride + 4 * idx];  // r2r
  float4 h1 = *(const float4*)&hseq[1 * pstride + 4 * idx];  // r2i
  float4 h2 = *(const float4*)&hseq[2 * pstride + 4 * idx];  // i2r
  float4 h3 = *(const float4*)&hseq[3 * pstride + 4 * idx];  // i2i
  float4 re, im;
  re.x = h0.x - h3.x; re.y = h0.y - h3.y; re.z = h0.z - h3.z; re.w = h0.w - h3.w;
  im.x = h1.x + h2.x; im.y = h1.y + h2.y; im.z = h1.z + h2.z; im.w = h1.w + h2.w;
  *(float4*)&out[(size_t)t0 * 512 + 4 * idx] = re;
  *(float4*)&out[(size_t)4096000 + (size_t)t0 * 512 + 4 * idx] = im;
}

// ---------------- final states: h from last hseq step, c from cs ----------------
__global__ void final_kernel(const float* __restrict__ hseq, const float* __restrict__ cs,
                             float* __restrict__ out, int chunk) {
  int idx = blockIdx.x * blockDim.x + threadIdx.x;
  if (idx < 2048) {  // p*512+u
    const int p = idx >> 9, u = idx & 511;
    out[8192000 + 2 * (size_t)idx + 0] = hseq[((size_t)p * chunk + (chunk - 1)) * 512 + u];
    out[8192000 + 2 * (size_t)idx + 1] = cs[idx];
  }
}

extern "C" void kernel_launch(void* const* d_in, const int* in_sizes, int n_in,
                              void* d_out, int out_size, void* d_ws, size_t ws_size,
                              hipStream_t stream) {
  (void)in_sizes; (void)n_in;
  const float* in_real   = (const float*)d_in[0];
  const float* in_imag   = (const float*)d_in[1];
  const float* in_states = (const float*)d_in[2];
  const float* Wr = (const float*)d_in[3];
  const float* Rr = (const float*)d_in[4];
  const float* br = (const float*)d_in[5];
  const float* Wi = (const float*)d_in[6];
  const float* Ri = (const float*)d_in[7];
  const float* bi = (const float*)d_in[8];
  float* out = (float*)d_out;

  // ws layout: h pair double-buffer [2][2048] x 8B (32KB) | c [4][512] (8KB)
  //            | pad to 64KB | xz [4][chunk][2048] | hseq [4][chunk][512]
  ull* hp = (ull*)d_ws;
  float* cs = (float*)((char*)d_ws + 32768);
  float* xz = (float*)((char*)d_ws + 65536);

  int chunk = 2000;  // halvings all divide 8000
  // per-chunk bytes: xz 4*2048*4*chunk + hseq 4*512*4*chunk = 40960*chunk
  while (chunk > 125 && (size_t)chunk * 40960 + 65536 > ws_size) chunk >>= 1;
  float* hseq = xz + (size_t)4 * chunk * 2048;

  hipMemsetAsync(d_out, 0, (size_t)out_size * sizeof(float), stream);
  init_kernel<<<2, 1024, 0, stream>>>(in_states, hp, cs);
  for (int t0 = 0; t0 < T_TOTAL; t0 += chunk) {
    dim3 pgrid(2048 / 64, (chunk + 63) / 64, 4);
    proj_kernel<<<pgrid, 256, 0, stream>>>(in_real, in_imag, Wr, br, Wi, bi, xz, t0, chunk);
    recur_kernel<<<128, 256, 0, stream>>>(xz, Rr, Ri, hp, cs, hseq, t0, chunk);
    combine_kernel<<<(chunk * 512 / 4 + 255) / 256, 256, 0, stream>>>(hseq, out, t0, chunk);
  }
  final_kernel<<<2, 1024, 0, stream>>>(hseq, cs, out, chunk);
}